// Round 21
// baseline (415.894 us; speedup 1.0000x reference)
//
#include <hip/hip_runtime.h>

// Problem constants
#define N_NODESC 50000
#define N_EDGESC 800000
#define EPSF 1e-5f
#define NTILE 782                   // ceil(50000/64)  (agg tiles)
#define NTBLK 1563                  // ceil(50000/32)  (k_T9 blocks)
#define TROW  576                   // 9*64 ushorts per T9b row
#define NKEY9 450000                // 50000*9
#define NKPAD9 450048               // 1758*256
#define NHBLK9 1758
#define NEBLK 3125                  // 800000/256
#define GCHUNK 32

typedef __attribute__((ext_vector_type(8))) short short8;
typedef __attribute__((ext_vector_type(8))) ushort ushort8;
typedef __attribute__((ext_vector_type(16))) float f32x16;

// ---- ws layout (bytes), total ~118 MB ----
#define WS_SCALE 0
#define WS_SHIFT 256
#define WS_BSUM  512                  // 1758 int
#define WS_PBUF  8704                 // 782*128 f32 -> ends 409088
#define WS_HIST  409600               // 450048 int
#define WS_FILL  2209792              // 450048 int
#define WS_SEG   4009984              // 450049 int -> pad
#define WS_ELIST 5810432              // 800000 int (ushort-offset into T9b)
#define WS_GHI   9010432              // 147456 B
#define WS_GLO   9157888              // 147456 B
#define WS_BVEC  9305344              // 9*64 f32 -> pad
#define WS_ACTHI 9308160              // 50016*128 ushort
#define WS_ACTLO 22112256             // 50016*128 ushort
#define WS_OUTB  34916352             // 50000*64 f32
#define WS_HRES  47716352             // 50016*64 f32 (residual, f32)
#define WS_T9B   60520448             // 50016*576 ushort = 57.6 MB

__device__ __forceinline__ ushort bf_hi(float v) {
    return (ushort)(__float_as_uint(v) >> 16);
}
__device__ __forceinline__ ushort bf_lo(float v) {
    const unsigned b = __float_as_uint(v);
    const float lof = v - __uint_as_float(b & 0xFFFF0000u);
    return (ushort)(__float_as_uint(lof) >> 16);
}
__device__ __forceinline__ ushort bf_rne(float v) {
    const unsigned b = __float_as_uint(v);
    return (ushort)((b + 0x7FFFu + ((b >> 16) & 1u)) >> 16);
}
__device__ __forceinline__ float bf_f(ushort u) {
    return __uint_as_float((unsigned)u << 16);
}

// slot: identity combos (label_dst==label_src) -> 8; else c-4 in [0,8)
__device__ __forceinline__ int edge_slot(int ld, int ls, int bx) {
    return (ld == ls) ? 8 : ((ld * 2 + ls) * 4 + bx - 4);
}

// ---------------- histogram over (dst, slot) ----------------
__global__ __launch_bounds__(256)
void k_hist9(const int* __restrict__ src, const int* __restrict__ dst,
             const int* __restrict__ labels, const int* __restrict__ bidx,
             int* __restrict__ hist)
{
    const int e = blockIdx.x * 256 + threadIdx.x;
    if (e >= N_EDGESC) return;
    const int s = src[e], d = dst[e];
    const int slot = edge_slot(labels[d], labels[s], bidx[e]);
    atomicAdd(&hist[d * 9 + slot], 1);
}

// ---------------- 3-level scan ----------------
__global__ __launch_bounds__(256)
void k_bsum(const int* __restrict__ hist, int* __restrict__ bsum)
{
    __shared__ int s[256];
    const int i = blockIdx.x * 256 + threadIdx.x;
    s[threadIdx.x] = hist[i];
    __syncthreads();
    for (int off = 128; off > 0; off >>= 1) {
        if (threadIdx.x < off) s[threadIdx.x] += s[threadIdx.x + off];
        __syncthreads();
    }
    if (threadIdx.x == 0) bsum[blockIdx.x] = s[0];
}

__global__ __launch_bounds__(1024)
void k_bscan2(int* __restrict__ bsum)
{
    __shared__ int s[1024];
    const int t = threadIdx.x;
    int v[4]; int tot = 0;
#pragma unroll
    for (int j = 0; j < 4; ++j) {
        const int i = t * 4 + j;
        v[j] = (i < NHBLK9) ? bsum[i] : 0;
        tot += v[j];
    }
    s[t] = tot; __syncthreads();
    for (int off = 1; off < 1024; off <<= 1) {
        const int x = (t >= off) ? s[t - off] : 0;
        __syncthreads();
        s[t] += x;
        __syncthreads();
    }
    int base = s[t] - tot;
#pragma unroll
    for (int j = 0; j < 4; ++j) {
        const int i = t * 4 + j;
        if (i < NHBLK9) bsum[i] = base;
        base += v[j];
    }
}

__global__ __launch_bounds__(256)
void k_escan2(const int* __restrict__ hist, const int* __restrict__ bsum,
              int* __restrict__ seg)
{
    __shared__ int s[256];
    const int t = threadIdx.x;
    const int i = blockIdx.x * 256 + t;
    const int v = hist[i];
    s[t] = v; __syncthreads();
    for (int off = 1; off < 256; off <<= 1) {
        const int x = (t >= off) ? s[t - off] : 0;
        __syncthreads();
        s[t] += x;
        __syncthreads();
    }
    seg[i] = bsum[blockIdx.x] + s[t] - v;
}

__global__ __launch_bounds__(256)
void k_scat9(const int* __restrict__ src, const int* __restrict__ dst,
             const int* __restrict__ labels, const int* __restrict__ bidx,
             const int* __restrict__ seg, int* __restrict__ fill,
             int* __restrict__ elist)
{
    const int e = blockIdx.x * 256 + threadIdx.x;
    if (e >= N_EDGESC) return;
    const int s = src[e], d = dst[e];
    const int slot = edge_slot(labels[d], labels[s], bidx[e]);
    const int k = d * 9 + slot;
    const int pos = seg[k] + atomicAdd(&fill[k], 1);
    elist[pos] = s * TROW + slot * 64;     // ushort offset into T9b
}

// ---- per-layer: G_slot = M_{slot+4} @ W^T (slot<8), W^T (slot 8); + bias ----
__global__ __launch_bounds__(256)
void k_gfrag(const float* __restrict__ M, const float* __restrict__ W,
             const float* __restrict__ b, ushort* __restrict__ Ghi,
             ushort* __restrict__ Glo, float* __restrict__ bvec, const int F)
{
    __shared__ float Ml[4096];
    const int slot = blockIdx.x >> 5;
    const int chunk = blockIdx.x & 31;
    const int tid = threadIdx.x;
    const int KS = F >> 4;
    if (slot < 8) {
        const float* __restrict__ Mc = M + (slot + 4) * 4096;
        for (int i = tid; i < 4096; i += 256) Ml[i] = Mc[i];
    }
    __syncthreads();
    if (chunk == 0 && tid < 64) {
        float acc;
        if (slot < 8) {
            acc = 0.f;
            for (int e = 0; e < 64; ++e) acc += Ml[tid * 64 + e] * b[e];
        } else acc = b[tid];
        bvec[slot * 64 + tid] = acc;
    }
    const int total = 2 * KS * 512;
    const int per = (total + 31) >> 5;
    const int uend = min((chunk + 1) * per, total);
    for (int u = chunk * per + tid; u < uend; u += 256) {
        const int j = u & 7;
        const int lane = (u >> 3) & 63;
        const int s = (u >> 9) % KS;
        const int t = u / (KS * 512);
        const int r = (lane & 31) + 32 * t;
        const int f = 16 * s + 8 * (lane >> 5) + j;
        float g;
        if (slot < 8) {
            g = 0.f;
            const float* __restrict__ wr = W + f * 64;
            const float* __restrict__ mr = Ml + r * 64;
#pragma unroll 16
            for (int e = 0; e < 64; ++e) g += mr[e] * wr[e];
        } else {
            g = W[f * 64 + r];
        }
        const int fid = ((slot * 2 + t) * KS + s) * 64 + lane;
        Ghi[fid * 8 + j] = bf_hi(g);
        Glo[fid * 8 + j] = bf_lo(g);
    }
}

// ---------------- act split: layer 0 (x direct) ----------------
__global__ __launch_bounds__(256)
void k_actx(const float* __restrict__ x, ushort* __restrict__ ahi,
            ushort* __restrict__ alo)
{
    const int t = blockIdx.x * 256 + threadIdx.x;
    if (t * 4 >= N_NODESC * 128) return;
    const float4 v = *(const float4*)&x[t * 4];
    ushort4 h4, l4;
    h4.x = bf_hi(v.x); h4.y = bf_hi(v.y); h4.z = bf_hi(v.z); h4.w = bf_hi(v.w);
    l4.x = bf_lo(v.x); l4.y = bf_lo(v.y); l4.z = bf_lo(v.z); l4.w = bf_lo(v.w);
    *(ushort4*)&ahi[t * 4] = h4;
    *(ushort4*)&alo[t * 4] = l4;
}

// ---------------- act: LN-apply + relu + split (layers 1,2) ----------------
__global__ __launch_bounds__(256)
void k_act(const float* __restrict__ outb, const float* __restrict__ scale,
           const float* __restrict__ shift, ushort* __restrict__ ahi,
           ushort* __restrict__ alo)
{
    const int t = blockIdx.x * 256 + threadIdx.x;
    if (t * 4 >= N_NODESC * 64) return;
    const int e0 = (t * 4) & 63;
    const float4 v = *(const float4*)&outb[t * 4];
    const float a0 = fmaxf(v.x * scale[e0] + shift[e0], 0.f);
    const float a1 = fmaxf(v.y * scale[e0 + 1] + shift[e0 + 1], 0.f);
    const float a2 = fmaxf(v.z * scale[e0 + 2] + shift[e0 + 2], 0.f);
    const float a3 = fmaxf(v.w * scale[e0 + 3] + shift[e0 + 3], 0.f);
    ushort4 h4, l4;
    h4.x = bf_hi(a0); h4.y = bf_hi(a1); h4.z = bf_hi(a2); h4.w = bf_hi(a3);
    l4.x = bf_lo(a0); l4.y = bf_lo(a1); l4.z = bf_lo(a2); l4.w = bf_lo(a3);
    *(ushort4*)&ahi[t * 4] = h4;
    *(ushort4*)&alo[t * 4] = l4;
}

// ---------------- 9-slot transform table -> bf16 T9b (+ f32 hres slot 8) ----
// bf16 LDS staging (16 KB/block) -> 6 blocks/CU residency.
__global__ __launch_bounds__(256, 6)
void k_T9(const ushort* __restrict__ ahi, const ushort* __restrict__ alo,
          const ushort* __restrict__ Ghi, const ushort* __restrict__ Glo,
          const float* __restrict__ bvec, ushort* __restrict__ T9b,
          float* __restrict__ hres, const int KS, const int F)
{
    __shared__ ushort msg[4][2048];       // per-wave 32 nodes x 64 feats bf16 (16 KB)
    const int tid = threadIdx.x;
    const int w = tid >> 6, lane = tid & 63;
    const int col = lane & 31, hig = lane >> 5;
    const int node = blockIdx.x * 32 + col;
    const ushort* __restrict__ rh = ahi + (long)node * F + hig * 8;
    const ushort* __restrict__ rl = alo + (long)node * F + hig * 8;
    ushort* __restrict__ msgw = msg[w];
    ushort* __restrict__ Tb = T9b + (long)blockIdx.x * 32 * TROW;

    for (int slot = w; slot < 9; slot += 4) {
        f32x16 c0, c1;
#pragma unroll
        for (int r = 0; r < 16; ++r) {
            const int fp = (r & 3) + 8 * (r >> 2) + 4 * hig;
            c0[r] = bvec[slot * 64 + fp];
            c1[r] = bvec[slot * 64 + fp + 32];
        }
        for (int s = 0; s < KS; ++s) {
            const int fid0 = ((slot * 2 + 0) * KS + s) * 64 + lane;
            const int fid1 = ((slot * 2 + 1) * KS + s) * 64 + lane;
            const short8 a0h = *(const short8*)&Ghi[fid0 * 8];
            const short8 a1h = *(const short8*)&Ghi[fid1 * 8];
            const short8 a0l = *(const short8*)&Glo[fid0 * 8];
            const short8 a1l = *(const short8*)&Glo[fid1 * 8];
            const short8 bh = *(const short8*)&rh[s * 16];
            const short8 bl = *(const short8*)&rl[s * 16];
            c0 = __builtin_amdgcn_mfma_f32_32x32x16_bf16(a0h, bh, c0, 0, 0, 0);
            c1 = __builtin_amdgcn_mfma_f32_32x32x16_bf16(a1h, bh, c1, 0, 0, 0);
            c0 = __builtin_amdgcn_mfma_f32_32x32x16_bf16(a0h, bl, c0, 0, 0, 0);
            c1 = __builtin_amdgcn_mfma_f32_32x32x16_bf16(a1h, bl, c1, 0, 0, 0);
            c0 = __builtin_amdgcn_mfma_f32_32x32x16_bf16(a0l, bh, c0, 0, 0, 0);
            c1 = __builtin_amdgcn_mfma_f32_32x32x16_bf16(a1l, bh, c1, 0, 0, 0);
        }

        // stage C tile to LDS in bf16 (same XOR pattern, ushort units)
        const int sw = (col & 7) << 3;
        const int cb = col * 64;
#pragma unroll
        for (int rq = 0; rq < 4; ++rq) {
            const int fb = 8 * rq + 4 * hig;
            ushort4 p0, p1;
            p0.x = bf_rne(c0[4*rq]);     p0.y = bf_rne(c0[4*rq+1]);
            p0.z = bf_rne(c0[4*rq+2]);   p0.w = bf_rne(c0[4*rq+3]);
            p1.x = bf_rne(c1[4*rq]);     p1.y = bf_rne(c1[4*rq+1]);
            p1.z = bf_rne(c1[4*rq+2]);   p1.w = bf_rne(c1[4*rq+3]);
            *(ushort4*)&msgw[cb + (fb ^ sw)] = p0;
            *(ushort4*)&msgw[cb + ((fb + 32) ^ sw)] = p1;
        }
        // f32 residual straight from registers (slot 8 only; contiguous 16B rows)
        if (slot == 8) {
            float* __restrict__ hrow = hres + (long)node * 64;
#pragma unroll
            for (int rq = 0; rq < 4; ++rq) {
                const int fb = 8 * rq + 4 * hig;
                float4 v0 = {c0[4*rq], c0[4*rq+1], c0[4*rq+2], c0[4*rq+3]};
                float4 v1 = {c1[4*rq], c1[4*rq+1], c1[4*rq+2], c1[4*rq+3]};
                *(float4*)&hrow[fb] = v0;
                *(float4*)&hrow[fb + 32] = v1;
            }
        }
        asm volatile("s_waitcnt lgkmcnt(0)" ::: "memory");

        // coalesced bf16 store-out: 8 lanes cover one row's 128B
#pragma unroll
        for (int i = 0; i < 4; ++i) {
            const int idx = i * 64 + lane;
            const int row = idx >> 3, oct = idx & 7;
            const int qs = (row & 7) << 3;
            const int po = (oct * 8) ^ qs;
            const ushort4 ua = *(const ushort4*)&msgw[row * 64 + po];
            const ushort4 ub = *(const ushort4*)&msgw[row * 64 + po + 4];
            ushort8 u;
            u[0] = ua.x; u[1] = ua.y; u[2] = ua.z; u[3] = ua.w;
            u[4] = ub.x; u[5] = ub.y; u[6] = ub.z; u[7] = ub.w;
            *(ushort8*)&Tb[(long)row * TROW + slot * 64 + oct * 8] = u;
        }
        asm volatile("s_waitcnt lgkmcnt(0)" ::: "memory");
    }
}

// ---------------- gather-aggregate (bf16) + residual(f32) + LN partials -----
__global__ __launch_bounds__(256, 4)
void k_agg2(const ushort* __restrict__ T9b, const float* __restrict__ hres,
            const int* __restrict__ elist, const int* __restrict__ seg,
            float* __restrict__ outb, float* __restrict__ pbuf)
{
    __shared__ float red[2][4][64];
    const int tid = threadIdx.x;
    const int w = tid >> 6, lane = tid & 63;
    const int dl = lane >> 2, fq = lane & 3;
    const int tile = blockIdx.x;
    const int gd = tile * 64 + w * 16 + dl;

    float4 a0 = {0,0,0,0}, a1 = a0, a2 = a0, a3 = a0;

    if (gd < N_NODESC) {
        const int p0 = seg[gd * 9];
        const int p1 = seg[gd * 9 + 9];
        const ushort* __restrict__ Tf = T9b + 16 * fq;
        int p = p0;
        for (; p + 4 <= p1; p += 4) {
            const long t0 = (long)elist[p];
            const long t1 = (long)elist[p + 1];
            const long t2 = (long)elist[p + 2];
            const long t3 = (long)elist[p + 3];
            const ushort8 u0a = *(const ushort8*)&Tf[t0];
            const ushort8 u0b = *(const ushort8*)&Tf[t0 + 8];
            const ushort8 u1a = *(const ushort8*)&Tf[t1];
            const ushort8 u1b = *(const ushort8*)&Tf[t1 + 8];
            const ushort8 u2a = *(const ushort8*)&Tf[t2];
            const ushort8 u2b = *(const ushort8*)&Tf[t2 + 8];
            const ushort8 u3a = *(const ushort8*)&Tf[t3];
            const ushort8 u3b = *(const ushort8*)&Tf[t3 + 8];
#pragma unroll
            for (int k = 0; k < 4; ++k) {
                (&a0.x)[k] += bf_f(u0a[k]) + bf_f(u1a[k]) + bf_f(u2a[k]) + bf_f(u3a[k]);
                (&a1.x)[k] += bf_f(u0a[k+4]) + bf_f(u1a[k+4]) + bf_f(u2a[k+4]) + bf_f(u3a[k+4]);
                (&a2.x)[k] += bf_f(u0b[k]) + bf_f(u1b[k]) + bf_f(u2b[k]) + bf_f(u3b[k]);
                (&a3.x)[k] += bf_f(u0b[k+4]) + bf_f(u1b[k+4]) + bf_f(u2b[k+4]) + bf_f(u3b[k+4]);
            }
        }
        for (; p < p1; ++p) {
            const long t0 = (long)elist[p];
            const ushort8 ua = *(const ushort8*)&Tf[t0];
            const ushort8 ub = *(const ushort8*)&Tf[t0 + 8];
#pragma unroll
            for (int k = 0; k < 4; ++k) {
                (&a0.x)[k] += bf_f(ua[k]);
                (&a1.x)[k] += bf_f(ua[k+4]);
                (&a2.x)[k] += bf_f(ub[k]);
                (&a3.x)[k] += bf_f(ub[k+4]);
            }
        }
    }

    // ---- epilogue: residual (hres f32) + store + LN partials ----
    float4 v[4] = {a0, a1, a2, a3};
    if (gd < N_NODESC) {
        const float4* __restrict__ hr =
            (const float4*)(hres + (long)gd * 64 + 16 * fq);
        float4* __restrict__ ob = (float4*)(outb + (long)gd * 64 + 16 * fq);
#pragma unroll
        for (int u = 0; u < 4; ++u) {
            const float4 r = hr[u];
            v[u].x += r.x; v[u].y += r.y; v[u].z += r.z; v[u].w += r.w;
            ob[u] = v[u];
        }
    } else {
#pragma unroll
        for (int u = 0; u < 4; ++u) v[u] = make_float4(0.f, 0.f, 0.f, 0.f);
    }
    float s1[16], s2[16];
#pragma unroll
    for (int u = 0; u < 4; ++u) {
        s1[4*u+0] = v[u].x; s2[4*u+0] = v[u].x * v[u].x;
        s1[4*u+1] = v[u].y; s2[4*u+1] = v[u].y * v[u].y;
        s1[4*u+2] = v[u].z; s2[4*u+2] = v[u].z * v[u].z;
        s1[4*u+3] = v[u].w; s2[4*u+3] = v[u].w * v[u].w;
    }
#pragma unroll
    for (int j = 0; j < 16; ++j) {
        s1[j] += __shfl_xor(s1[j], 4);  s2[j] += __shfl_xor(s2[j], 4);
        s1[j] += __shfl_xor(s1[j], 8);  s2[j] += __shfl_xor(s2[j], 8);
        s1[j] += __shfl_xor(s1[j], 16); s2[j] += __shfl_xor(s2[j], 16);
        s1[j] += __shfl_xor(s1[j], 32); s2[j] += __shfl_xor(s2[j], 32);
    }
    if (dl == 0) {
#pragma unroll
        for (int j = 0; j < 16; ++j) {
            red[0][w][16 * fq + j] = s1[j];
            red[1][w][16 * fq + j] = s2[j];
        }
    }
    __syncthreads();
    if (tid < 64) {
        const float t1 = red[0][0][tid] + red[0][1][tid] + red[0][2][tid] + red[0][3][tid];
        const float t2 = red[1][0][tid] + red[1][1][tid] + red[1][2][tid] + red[1][3][tid];
        pbuf[tile * 128 + tid] = t1;
        pbuf[tile * 128 + 64 + tid] = t2;
    }
}

// ---------------- reduce LN partials -> scale/shift ----------------
__global__ __launch_bounds__(1024)
void k_norm2(const float* __restrict__ pbuf, const float* __restrict__ g,
             const float* __restrict__ be, float* __restrict__ scale,
             float* __restrict__ shift)
{
    __shared__ float s[1024];
    const int t = threadIdx.x, j = t & 127, gg = t >> 7;
    float a = 0.f;
    for (int b = gg; b < NTILE; b += 8) a += pbuf[b * 128 + j];
    s[t] = a;
    __syncthreads();
    if (t < 128) {
        float tot = 0.f;
#pragma unroll
        for (int k = 0; k < 8; ++k) tot += s[j + 128 * k];
        s[t] = tot;
    }
    __syncthreads();
    if (t < 64) {
        const double mu  = (double)s[t] / (double)N_NODESC;
        const double var = (double)s[64 + t] / (double)N_NODESC - mu * mu;
        const double sc  = (double)g[t] / sqrt(var + (double)EPSF);
        scale[t] = (float)sc;
        shift[t] = (float)((double)be[t] - mu * sc);
    }
}

// ---------------- final projection (LN apply fused) ----------------
__global__ __launch_bounds__(256)
void k_out(const float* __restrict__ outb, const float* __restrict__ scale,
           const float* __restrict__ shift, const float* __restrict__ resW,
           const float* __restrict__ resb, float* __restrict__ out)
{
    const int n = blockIdx.x * 256 + threadIdx.x;
    if (n >= N_NODESC) return;
    float a0 = resb[0], a1 = resb[1];
    const float* __restrict__ r = outb + (long)n * 64;
#pragma unroll 8
    for (int e = 0; e < 64; ++e) {
        const float v = fmaxf(r[e] * scale[e] + shift[e], 0.f);
        a0 += v * resW[2 * e];
        a1 += v * resW[2 * e + 1];
    }
    out[2 * n] = a0;
    out[2 * n + 1] = a1;
}

extern "C" void kernel_launch(void* const* d_in, const int* in_sizes, int n_in,
                              void* d_out, int out_size, void* d_ws, size_t ws_size,
                              hipStream_t stream)
{
    const float* x      = (const float*)d_in[0];
    const float* M      = (const float*)d_in[1];
    const int*   src    = (const int*)d_in[2];
    const int*   dst    = (const int*)d_in[3];
    const int*   labels = (const int*)d_in[4];
    const int*   bidx   = (const int*)d_in[5];
    const float* resW   = (const float*)d_in[18];
    const float* resb   = (const float*)d_in[19];
    float* out = (float*)d_out;

    char* ws = (char*)d_ws;
    float*  scale = (float*)(ws + WS_SCALE);
    float*  shift = (float*)(ws + WS_SHIFT);
    int*    bsum  = (int*)(ws + WS_BSUM);
    float*  pbuf  = (float*)(ws + WS_PBUF);
    int*    hist  = (int*)(ws + WS_HIST);
    int*    fill  = (int*)(ws + WS_FILL);
    int*    seg   = (int*)(ws + WS_SEG);
    int*    elist = (int*)(ws + WS_ELIST);
    ushort* Ghi   = (ushort*)(ws + WS_GHI);
    ushort* Glo   = (ushort*)(ws + WS_GLO);
    float*  bvec  = (float*)(ws + WS_BVEC);
    ushort* ahi   = (ushort*)(ws + WS_ACTHI);
    ushort* alo   = (ushort*)(ws + WS_ACTLO);
    float*  outb  = (float*)(ws + WS_OUTB);
    float*  hres  = (float*)(ws + WS_HRES);
    ushort* T9b   = (ushort*)(ws + WS_T9B);

    // ---- preprocessing (graph constant across layers) ----
    hipMemsetAsync(hist, 0, 2 * (size_t)NKPAD9 * sizeof(int), stream);  // hist+fill
    k_hist9<<<NEBLK, 256, 0, stream>>>(src, dst, labels, bidx, hist);
    k_bsum<<<NHBLK9, 256, 0, stream>>>(hist, bsum);
    k_bscan2<<<1, 1024, 0, stream>>>(bsum);
    k_escan2<<<NHBLK9, 256, 0, stream>>>(hist, bsum, seg);
    k_scat9<<<NEBLK, 256, 0, stream>>>(src, dst, labels, bidx, seg, fill, elist);

    for (int l = 0; l < 3; ++l) {
        const float* W  = (const float*)d_in[6 + 4 * l];
        const float* b  = (const float*)d_in[7 + 4 * l];
        const float* g  = (const float*)d_in[8 + 4 * l];
        const float* be = (const float*)d_in[9 + 4 * l];
        const int F = (l == 0) ? 128 : 64;

        k_gfrag<<<9 * GCHUNK, 256, 0, stream>>>(M, W, b, Ghi, Glo, bvec, F);
        if (l == 0) {
            k_actx<<<6250, 256, 0, stream>>>(x, ahi, alo);
        } else {
            k_act<<<3125, 256, 0, stream>>>(outb, scale, shift, ahi, alo);
        }
        k_T9<<<NTBLK, 256, 0, stream>>>(ahi, alo, Ghi, Glo, bvec, T9b, hres,
                                        F >> 4, F);
        k_agg2<<<NTILE, 256, 0, stream>>>(T9b, hres, elist, seg, outb, pbuf);
        k_norm2<<<1, 1024, 0, stream>>>(pbuf, g, be, scale, shift);
    }
    k_out<<<(N_NODESC + 255) / 256, 256, 0, stream>>>(outb, scale, shift, resW, resb, out);
    (void)in_sizes; (void)n_in; (void)out_size; (void)ws_size;
}

// Round 22
// 403.623 us; speedup vs baseline: 1.0304x; 1.0304x over previous
//
#include <hip/hip_runtime.h>

// Problem constants
#define N_NODESC 50000
#define N_EDGESC 800000
#define EPSF 1e-5f
#define NTILE 782                   // ceil(50000/64)  (agg tiles)
#define NTBLK 1563                  // ceil(50000/32)  (k_T9 blocks)
#define TROW  576                   // 9*64 ushorts per T9b row
#define NKEY9 450000                // 50000*9
#define NKPAD9 450048               // 1758*256
#define NHBLK9 1758
#define NEBLK 3125                  // 800000/256
#define GCHUNK 32

typedef __attribute__((ext_vector_type(8))) short short8;
typedef __attribute__((ext_vector_type(8))) ushort ushort8;
typedef __attribute__((ext_vector_type(16))) float f32x16;

// ---- ws layout (bytes), total ~118 MB ----
#define WS_SCALE 0
#define WS_SHIFT 256
#define WS_BSUM  512                  // 1758 int
#define WS_PBUF  8704                 // 782*128 f32 -> ends 409088
#define WS_HIST  409600               // 450048 int
#define WS_FILL  2209792              // 450048 int
#define WS_SEG   4009984              // 450049 int -> pad
#define WS_ELIST 5810432              // 800000 int (ushort-offset into T9b)
#define WS_GHI   9010432              // 147456 B
#define WS_GLO   9157888              // 147456 B
#define WS_BVEC  9305344              // 9*64 f32 -> pad
#define WS_ACTHI 9308160              // 50016*128 ushort
#define WS_ACTLO 22112256             // 50016*128 ushort
#define WS_OUTB  34916352             // 50000*64 f32
#define WS_HRES  47716352             // 50016*64 f32 (residual, f32)
#define WS_T9B   60520448             // 50016*576 ushort = 57.6 MB

__device__ __forceinline__ ushort bf_hi(float v) {
    return (ushort)(__float_as_uint(v) >> 16);
}
__device__ __forceinline__ ushort bf_lo(float v) {
    const unsigned b = __float_as_uint(v);
    const float lof = v - __uint_as_float(b & 0xFFFF0000u);
    return (ushort)(__float_as_uint(lof) >> 16);
}
__device__ __forceinline__ ushort bf_rne(float v) {
    const unsigned b = __float_as_uint(v);
    return (ushort)((b + 0x7FFFu + ((b >> 16) & 1u)) >> 16);
}
__device__ __forceinline__ float bf_f(ushort u) {
    return __uint_as_float((unsigned)u << 16);
}

// slot: identity combos (label_dst==label_src) -> 8; else c-4 in [0,8)
__device__ __forceinline__ int edge_slot(int ld, int ls, int bx) {
    return (ld == ls) ? 8 : ((ld * 2 + ls) * 4 + bx - 4);
}

// ---------------- histogram over (dst, slot) ----------------
__global__ __launch_bounds__(256)
void k_hist9(const int* __restrict__ src, const int* __restrict__ dst,
             const int* __restrict__ labels, const int* __restrict__ bidx,
             int* __restrict__ hist)
{
    const int e = blockIdx.x * 256 + threadIdx.x;
    if (e >= N_EDGESC) return;
    const int s = src[e], d = dst[e];
    const int slot = edge_slot(labels[d], labels[s], bidx[e]);
    atomicAdd(&hist[d * 9 + slot], 1);
}

// ---------------- 3-level scan ----------------
__global__ __launch_bounds__(256)
void k_bsum(const int* __restrict__ hist, int* __restrict__ bsum)
{
    __shared__ int s[256];
    const int i = blockIdx.x * 256 + threadIdx.x;
    s[threadIdx.x] = hist[i];
    __syncthreads();
    for (int off = 128; off > 0; off >>= 1) {
        if (threadIdx.x < off) s[threadIdx.x] += s[threadIdx.x + off];
        __syncthreads();
    }
    if (threadIdx.x == 0) bsum[blockIdx.x] = s[0];
}

__global__ __launch_bounds__(1024)
void k_bscan2(int* __restrict__ bsum)
{
    __shared__ int s[1024];
    const int t = threadIdx.x;
    int v[4]; int tot = 0;
#pragma unroll
    for (int j = 0; j < 4; ++j) {
        const int i = t * 4 + j;
        v[j] = (i < NHBLK9) ? bsum[i] : 0;
        tot += v[j];
    }
    s[t] = tot; __syncthreads();
    for (int off = 1; off < 1024; off <<= 1) {
        const int x = (t >= off) ? s[t - off] : 0;
        __syncthreads();
        s[t] += x;
        __syncthreads();
    }
    int base = s[t] - tot;
#pragma unroll
    for (int j = 0; j < 4; ++j) {
        const int i = t * 4 + j;
        if (i < NHBLK9) bsum[i] = base;
        base += v[j];
    }
}

__global__ __launch_bounds__(256)
void k_escan2(const int* __restrict__ hist, const int* __restrict__ bsum,
              int* __restrict__ seg)
{
    __shared__ int s[256];
    const int t = threadIdx.x;
    const int i = blockIdx.x * 256 + t;
    const int v = hist[i];
    s[t] = v; __syncthreads();
    for (int off = 1; off < 256; off <<= 1) {
        const int x = (t >= off) ? s[t - off] : 0;
        __syncthreads();
        s[t] += x;
        __syncthreads();
    }
    seg[i] = bsum[blockIdx.x] + s[t] - v;
}

__global__ __launch_bounds__(256)
void k_scat9(const int* __restrict__ src, const int* __restrict__ dst,
             const int* __restrict__ labels, const int* __restrict__ bidx,
             const int* __restrict__ seg, int* __restrict__ fill,
             int* __restrict__ elist)
{
    const int e = blockIdx.x * 256 + threadIdx.x;
    if (e >= N_EDGESC) return;
    const int s = src[e], d = dst[e];
    const int slot = edge_slot(labels[d], labels[s], bidx[e]);
    const int k = d * 9 + slot;
    const int pos = seg[k] + atomicAdd(&fill[k], 1);
    elist[pos] = s * TROW + slot * 64;     // ushort offset into T9b
}

// ---- per-layer: G_slot = M_{slot+4} @ W^T (slot<8), W^T (slot 8); + bias ----
__global__ __launch_bounds__(256)
void k_gfrag(const float* __restrict__ M, const float* __restrict__ W,
             const float* __restrict__ b, ushort* __restrict__ Ghi,
             ushort* __restrict__ Glo, float* __restrict__ bvec, const int F)
{
    __shared__ float Ml[4096];
    const int slot = blockIdx.x >> 5;
    const int chunk = blockIdx.x & 31;
    const int tid = threadIdx.x;
    const int KS = F >> 4;
    if (slot < 8) {
        const float* __restrict__ Mc = M + (slot + 4) * 4096;
        for (int i = tid; i < 4096; i += 256) Ml[i] = Mc[i];
    }
    __syncthreads();
    if (chunk == 0 && tid < 64) {
        float acc;
        if (slot < 8) {
            acc = 0.f;
            for (int e = 0; e < 64; ++e) acc += Ml[tid * 64 + e] * b[e];
        } else acc = b[tid];
        bvec[slot * 64 + tid] = acc;
    }
    const int total = 2 * KS * 512;
    const int per = (total + 31) >> 5;
    const int uend = min((chunk + 1) * per, total);
    for (int u = chunk * per + tid; u < uend; u += 256) {
        const int j = u & 7;
        const int lane = (u >> 3) & 63;
        const int s = (u >> 9) % KS;
        const int t = u / (KS * 512);
        const int r = (lane & 31) + 32 * t;
        const int f = 16 * s + 8 * (lane >> 5) + j;
        float g;
        if (slot < 8) {
            g = 0.f;
            const float* __restrict__ wr = W + f * 64;
            const float* __restrict__ mr = Ml + r * 64;
#pragma unroll 16
            for (int e = 0; e < 64; ++e) g += mr[e] * wr[e];
        } else {
            g = W[f * 64 + r];
        }
        const int fid = ((slot * 2 + t) * KS + s) * 64 + lane;
        Ghi[fid * 8 + j] = bf_hi(g);
        Glo[fid * 8 + j] = bf_lo(g);
    }
}

// ---------------- act split: layer 0 (x direct) ----------------
__global__ __launch_bounds__(256)
void k_actx(const float* __restrict__ x, ushort* __restrict__ ahi,
            ushort* __restrict__ alo)
{
    const int t = blockIdx.x * 256 + threadIdx.x;
    if (t * 4 >= N_NODESC * 128) return;
    const float4 v = *(const float4*)&x[t * 4];
    ushort4 h4, l4;
    h4.x = bf_hi(v.x); h4.y = bf_hi(v.y); h4.z = bf_hi(v.z); h4.w = bf_hi(v.w);
    l4.x = bf_lo(v.x); l4.y = bf_lo(v.y); l4.z = bf_lo(v.z); l4.w = bf_lo(v.w);
    *(ushort4*)&ahi[t * 4] = h4;
    *(ushort4*)&alo[t * 4] = l4;
}

// ---------------- act: LN-apply + relu + split (layers 1,2) ----------------
__global__ __launch_bounds__(256)
void k_act(const float* __restrict__ outb, const float* __restrict__ scale,
           const float* __restrict__ shift, ushort* __restrict__ ahi,
           ushort* __restrict__ alo)
{
    const int t = blockIdx.x * 256 + threadIdx.x;
    if (t * 4 >= N_NODESC * 64) return;
    const int e0 = (t * 4) & 63;
    const float4 v = *(const float4*)&outb[t * 4];
    const float a0 = fmaxf(v.x * scale[e0] + shift[e0], 0.f);
    const float a1 = fmaxf(v.y * scale[e0 + 1] + shift[e0 + 1], 0.f);
    const float a2 = fmaxf(v.z * scale[e0 + 2] + shift[e0 + 2], 0.f);
    const float a3 = fmaxf(v.w * scale[e0 + 3] + shift[e0 + 3], 0.f);
    ushort4 h4, l4;
    h4.x = bf_hi(a0); h4.y = bf_hi(a1); h4.z = bf_hi(a2); h4.w = bf_hi(a3);
    l4.x = bf_lo(a0); l4.y = bf_lo(a1); l4.z = bf_lo(a2); l4.w = bf_lo(a3);
    *(ushort4*)&ahi[t * 4] = h4;
    *(ushort4*)&alo[t * 4] = l4;
}

// ---------------- 9-slot transform table -> bf16 T9b (+ f32 hres slot 8) ----
// R20 configuration: f32 LDS staging (32 KB), convert on store-out,
// hres written coalesced from LDS. (256,4).
__global__ __launch_bounds__(256, 4)
void k_T9(const ushort* __restrict__ ahi, const ushort* __restrict__ alo,
          const ushort* __restrict__ Ghi, const ushort* __restrict__ Glo,
          const float* __restrict__ bvec, ushort* __restrict__ T9b,
          float* __restrict__ hres, const int KS, const int F)
{
    __shared__ float msg[4][2048];        // per-wave 32 nodes x 64 feats (32 KB)
    const int tid = threadIdx.x;
    const int w = tid >> 6, lane = tid & 63;
    const int col = lane & 31, hig = lane >> 5;
    const int node = blockIdx.x * 32 + col;
    const ushort* __restrict__ rh = ahi + (long)node * F + hig * 8;
    const ushort* __restrict__ rl = alo + (long)node * F + hig * 8;
    float* __restrict__ msgw = msg[w];
    ushort* __restrict__ Tb = T9b + (long)blockIdx.x * 32 * TROW;
    float* __restrict__ hb = hres + (long)blockIdx.x * 32 * 64;

    for (int slot = w; slot < 9; slot += 4) {
        f32x16 c0, c1;
#pragma unroll
        for (int r = 0; r < 16; ++r) {
            const int fp = (r & 3) + 8 * (r >> 2) + 4 * hig;
            c0[r] = bvec[slot * 64 + fp];
            c1[r] = bvec[slot * 64 + fp + 32];
        }
        for (int s = 0; s < KS; ++s) {
            const int fid0 = ((slot * 2 + 0) * KS + s) * 64 + lane;
            const int fid1 = ((slot * 2 + 1) * KS + s) * 64 + lane;
            const short8 a0h = *(const short8*)&Ghi[fid0 * 8];
            const short8 a1h = *(const short8*)&Ghi[fid1 * 8];
            const short8 a0l = *(const short8*)&Glo[fid0 * 8];
            const short8 a1l = *(const short8*)&Glo[fid1 * 8];
            const short8 bh = *(const short8*)&rh[s * 16];
            const short8 bl = *(const short8*)&rl[s * 16];
            c0 = __builtin_amdgcn_mfma_f32_32x32x16_bf16(a0h, bh, c0, 0, 0, 0);
            c1 = __builtin_amdgcn_mfma_f32_32x32x16_bf16(a1h, bh, c1, 0, 0, 0);
            c0 = __builtin_amdgcn_mfma_f32_32x32x16_bf16(a0h, bl, c0, 0, 0, 0);
            c1 = __builtin_amdgcn_mfma_f32_32x32x16_bf16(a1h, bl, c1, 0, 0, 0);
            c0 = __builtin_amdgcn_mfma_f32_32x32x16_bf16(a0l, bh, c0, 0, 0, 0);
            c1 = __builtin_amdgcn_mfma_f32_32x32x16_bf16(a1l, bh, c1, 0, 0, 0);
        }

        // stage C tile to LDS (verified swizzle)
        const int sw = (col & 7) << 3;
        const int cb = col * 64;
#pragma unroll
        for (int rq = 0; rq < 4; ++rq) {
            const int fb = 8 * rq + 4 * hig;
            float4 v0 = {c0[4*rq], c0[4*rq+1], c0[4*rq+2], c0[4*rq+3]};
            float4 v1 = {c1[4*rq], c1[4*rq+1], c1[4*rq+2], c1[4*rq+3]};
            *(float4*)&msgw[cb + (fb ^ sw)] = v0;
            *(float4*)&msgw[cb + ((fb + 32) ^ sw)] = v1;
        }
        asm volatile("s_waitcnt lgkmcnt(0)" ::: "memory");

        // bf16 store-out: 8 lanes cover one row's 128B (RNE)
#pragma unroll
        for (int i = 0; i < 4; ++i) {
            const int idx = i * 64 + lane;
            const int row = idx >> 3, oct = idx & 7;
            const int qs = (row & 7) << 3;
            const float4 va = *(const float4*)&msgw[row * 64 + ((oct * 8) ^ qs)];
            const float4 vb = *(const float4*)&msgw[row * 64 + ((oct * 8 + 4) ^ qs)];
            ushort8 u;
            u[0] = bf_rne(va.x); u[1] = bf_rne(va.y);
            u[2] = bf_rne(va.z); u[3] = bf_rne(va.w);
            u[4] = bf_rne(vb.x); u[5] = bf_rne(vb.y);
            u[6] = bf_rne(vb.z); u[7] = bf_rne(vb.w);
            *(ushort8*)&Tb[(long)row * TROW + slot * 64 + oct * 8] = u;
        }
        if (slot == 8) {      // residual also in f32, coalesced from LDS
#pragma unroll
            for (int i = 0; i < 8; ++i) {
                const int idx = i * 64 + lane;
                const int row = idx >> 4, quad = idx & 15;
                const int qs = (row & 7) << 3;
                const float4 vv = *(const float4*)&msgw[row * 64 + ((quad * 4) ^ qs)];
                *(float4*)&hb[row * 64 + quad * 4] = vv;
            }
        }
        asm volatile("s_waitcnt lgkmcnt(0)" ::: "memory");
    }
}

// ---------------- gather-aggregate (bf16) + residual(f32) + LN partials -----
__global__ __launch_bounds__(256, 4)
void k_agg2(const ushort* __restrict__ T9b, const float* __restrict__ hres,
            const int* __restrict__ elist, const int* __restrict__ seg,
            float* __restrict__ outb, float* __restrict__ pbuf)
{
    __shared__ float red[2][4][64];
    const int tid = threadIdx.x;
    const int w = tid >> 6, lane = tid & 63;
    const int dl = lane >> 2, fq = lane & 3;
    const int tile = blockIdx.x;
    const int gd = tile * 64 + w * 16 + dl;

    float4 a0 = {0,0,0,0}, a1 = a0, a2 = a0, a3 = a0;

    if (gd < N_NODESC) {
        const int p0 = seg[gd * 9];
        const int p1 = seg[gd * 9 + 9];
        const ushort* __restrict__ Tf = T9b + 16 * fq;
        int p = p0;
        for (; p + 4 <= p1; p += 4) {
            const long t0 = (long)elist[p];
            const long t1 = (long)elist[p + 1];
            const long t2 = (long)elist[p + 2];
            const long t3 = (long)elist[p + 3];
            const ushort8 u0a = *(const ushort8*)&Tf[t0];
            const ushort8 u0b = *(const ushort8*)&Tf[t0 + 8];
            const ushort8 u1a = *(const ushort8*)&Tf[t1];
            const ushort8 u1b = *(const ushort8*)&Tf[t1 + 8];
            const ushort8 u2a = *(const ushort8*)&Tf[t2];
            const ushort8 u2b = *(const ushort8*)&Tf[t2 + 8];
            const ushort8 u3a = *(const ushort8*)&Tf[t3];
            const ushort8 u3b = *(const ushort8*)&Tf[t3 + 8];
#pragma unroll
            for (int k = 0; k < 4; ++k) {
                (&a0.x)[k] += bf_f(u0a[k]) + bf_f(u1a[k]) + bf_f(u2a[k]) + bf_f(u3a[k]);
                (&a1.x)[k] += bf_f(u0a[k+4]) + bf_f(u1a[k+4]) + bf_f(u2a[k+4]) + bf_f(u3a[k+4]);
                (&a2.x)[k] += bf_f(u0b[k]) + bf_f(u1b[k]) + bf_f(u2b[k]) + bf_f(u3b[k]);
                (&a3.x)[k] += bf_f(u0b[k+4]) + bf_f(u1b[k+4]) + bf_f(u2b[k+4]) + bf_f(u3b[k+4]);
            }
        }
        for (; p < p1; ++p) {
            const long t0 = (long)elist[p];
            const ushort8 ua = *(const ushort8*)&Tf[t0];
            const ushort8 ub = *(const ushort8*)&Tf[t0 + 8];
#pragma unroll
            for (int k = 0; k < 4; ++k) {
                (&a0.x)[k] += bf_f(ua[k]);
                (&a1.x)[k] += bf_f(ua[k+4]);
                (&a2.x)[k] += bf_f(ub[k]);
                (&a3.x)[k] += bf_f(ub[k+4]);
            }
        }
    }

    // ---- epilogue: residual (hres f32) + store + LN partials ----
    float4 v[4] = {a0, a1, a2, a3};
    if (gd < N_NODESC) {
        const float4* __restrict__ hr =
            (const float4*)(hres + (long)gd * 64 + 16 * fq);
        float4* __restrict__ ob = (float4*)(outb + (long)gd * 64 + 16 * fq);
#pragma unroll
        for (int u = 0; u < 4; ++u) {
            const float4 r = hr[u];
            v[u].x += r.x; v[u].y += r.y; v[u].z += r.z; v[u].w += r.w;
            ob[u] = v[u];
        }
    } else {
#pragma unroll
        for (int u = 0; u < 4; ++u) v[u] = make_float4(0.f, 0.f, 0.f, 0.f);
    }
    float s1[16], s2[16];
#pragma unroll
    for (int u = 0; u < 4; ++u) {
        s1[4*u+0] = v[u].x; s2[4*u+0] = v[u].x * v[u].x;
        s1[4*u+1] = v[u].y; s2[4*u+1] = v[u].y * v[u].y;
        s1[4*u+2] = v[u].z; s2[4*u+2] = v[u].z * v[u].z;
        s1[4*u+3] = v[u].w; s2[4*u+3] = v[u].w * v[u].w;
    }
#pragma unroll
    for (int j = 0; j < 16; ++j) {
        s1[j] += __shfl_xor(s1[j], 4);  s2[j] += __shfl_xor(s2[j], 4);
        s1[j] += __shfl_xor(s1[j], 8);  s2[j] += __shfl_xor(s2[j], 8);
        s1[j] += __shfl_xor(s1[j], 16); s2[j] += __shfl_xor(s2[j], 16);
        s1[j] += __shfl_xor(s1[j], 32); s2[j] += __shfl_xor(s2[j], 32);
    }
    if (dl == 0) {
#pragma unroll
        for (int j = 0; j < 16; ++j) {
            red[0][w][16 * fq + j] = s1[j];
            red[1][w][16 * fq + j] = s2[j];
        }
    }
    __syncthreads();
    if (tid < 64) {
        const float t1 = red[0][0][tid] + red[0][1][tid] + red[0][2][tid] + red[0][3][tid];
        const float t2 = red[1][0][tid] + red[1][1][tid] + red[1][2][tid] + red[1][3][tid];
        pbuf[tile * 128 + tid] = t1;
        pbuf[tile * 128 + 64 + tid] = t2;
    }
}

// ---------------- reduce LN partials -> scale/shift ----------------
__global__ __launch_bounds__(1024)
void k_norm2(const float* __restrict__ pbuf, const float* __restrict__ g,
             const float* __restrict__ be, float* __restrict__ scale,
             float* __restrict__ shift)
{
    __shared__ float s[1024];
    const int t = threadIdx.x, j = t & 127, gg = t >> 7;
    float a = 0.f;
    for (int b = gg; b < NTILE; b += 8) a += pbuf[b * 128 + j];
    s[t] = a;
    __syncthreads();
    if (t < 128) {
        float tot = 0.f;
#pragma unroll
        for (int k = 0; k < 8; ++k) tot += s[j + 128 * k];
        s[t] = tot;
    }
    __syncthreads();
    if (t < 64) {
        const double mu  = (double)s[t] / (double)N_NODESC;
        const double var = (double)s[64 + t] / (double)N_NODESC - mu * mu;
        const double sc  = (double)g[t] / sqrt(var + (double)EPSF);
        scale[t] = (float)sc;
        shift[t] = (float)((double)be[t] - mu * sc);
    }
}

// ---------------- final projection (LN apply fused) ----------------
__global__ __launch_bounds__(256)
void k_out(const float* __restrict__ outb, const float* __restrict__ scale,
           const float* __restrict__ shift, const float* __restrict__ resW,
           const float* __restrict__ resb, float* __restrict__ out)
{
    const int n = blockIdx.x * 256 + threadIdx.x;
    if (n >= N_NODESC) return;
    float a0 = resb[0], a1 = resb[1];
    const float* __restrict__ r = outb + (long)n * 64;
#pragma unroll 8
    for (int e = 0; e < 64; ++e) {
        const float v = fmaxf(r[e] * scale[e] + shift[e], 0.f);
        a0 += v * resW[2 * e];
        a1 += v * resW[2 * e + 1];
    }
    out[2 * n] = a0;
    out[2 * n + 1] = a1;
}

extern "C" void kernel_launch(void* const* d_in, const int* in_sizes, int n_in,
                              void* d_out, int out_size, void* d_ws, size_t ws_size,
                              hipStream_t stream)
{
    const float* x      = (const float*)d_in[0];
    const float* M      = (const float*)d_in[1];
    const int*   src    = (const int*)d_in[2];
    const int*   dst    = (const int*)d_in[3];
    const int*   labels = (const int*)d_in[4];
    const int*   bidx   = (const int*)d_in[5];
    const float* resW   = (const float*)d_in[18];
    const float* resb   = (const float*)d_in[19];
    float* out = (float*)d_out;

    char* ws = (char*)d_ws;
    float*  scale = (float*)(ws + WS_SCALE);
    float*  shift = (float*)(ws + WS_SHIFT);
    int*    bsum  = (int*)(ws + WS_BSUM);
    float*  pbuf  = (float*)(ws + WS_PBUF);
    int*    hist  = (int*)(ws + WS_HIST);
    int*    fill  = (int*)(ws + WS_FILL);
    int*    seg   = (int*)(ws + WS_SEG);
    int*    elist = (int*)(ws + WS_ELIST);
    ushort* Ghi   = (ushort*)(ws + WS_GHI);
    ushort* Glo   = (ushort*)(ws + WS_GLO);
    float*  bvec  = (float*)(ws + WS_BVEC);
    ushort* ahi   = (ushort*)(ws + WS_ACTHI);
    ushort* alo   = (ushort*)(ws + WS_ACTLO);
    float*  outb  = (float*)(ws + WS_OUTB);
    float*  hres  = (float*)(ws + WS_HRES);
    ushort* T9b   = (ushort*)(ws + WS_T9B);

    // ---- preprocessing (graph constant across layers) ----
    hipMemsetAsync(hist, 0, 2 * (size_t)NKPAD9 * sizeof(int), stream);  // hist+fill
    k_hist9<<<NEBLK, 256, 0, stream>>>(src, dst, labels, bidx, hist);
    k_bsum<<<NHBLK9, 256, 0, stream>>>(hist, bsum);
    k_bscan2<<<1, 1024, 0, stream>>>(bsum);
    k_escan2<<<NHBLK9, 256, 0, stream>>>(hist, bsum, seg);
    k_scat9<<<NEBLK, 256, 0, stream>>>(src, dst, labels, bidx, seg, fill, elist);

    for (int l = 0; l < 3; ++l) {
        const float* W  = (const float*)d_in[6 + 4 * l];
        const float* b  = (const float*)d_in[7 + 4 * l];
        const float* g  = (const float*)d_in[8 + 4 * l];
        const float* be = (const float*)d_in[9 + 4 * l];
        const int F = (l == 0) ? 128 : 64;

        k_gfrag<<<9 * GCHUNK, 256, 0, stream>>>(M, W, b, Ghi, Glo, bvec, F);
        if (l == 0) {
            k_actx<<<6250, 256, 0, stream>>>(x, ahi, alo);
        } else {
            k_act<<<3125, 256, 0, stream>>>(outb, scale, shift, ahi, alo);
        }
        k_T9<<<NTBLK, 256, 0, stream>>>(ahi, alo, Ghi, Glo, bvec, T9b, hres,
                                        F >> 4, F);
        k_agg2<<<NTILE, 256, 0, stream>>>(T9b, hres, elist, seg, outb, pbuf);
        k_norm2<<<1, 1024, 0, stream>>>(pbuf, g, be, scale, shift);
    }
    k_out<<<(N_NODESC + 255) / 256, 256, 0, stream>>>(outb, scale, shift, resW, resb, out);
    (void)in_sizes; (void)n_in; (void)out_size; (void)ws_size;
}